// Round 15
// baseline (497.249 us; speedup 1.0000x reference)
//
#include <hip/hip_runtime.h>
#include <math.h>

// Problem constants
constexpr int Nn  = 100000;  // nodes
constexpr int Ee  = 800000;  // edges
constexpr int Bb  = 4096;    // graphs
constexpr int Vv  = 103;     // vocab
constexpr int DIN = 200;     // embedding dim
constexpr int Hh  = 256;     // hidden

constexpr int SCHUNK = 1024;
constexpr int NSCAN  = (Nn + SCHUNK - 1)/SCHUNK;   // 98 blocks

using short8 = __attribute__((ext_vector_type(8))) short;
using f32x4  = __attribute__((ext_vector_type(4))) float;

__device__ __forceinline__ float sigf(float x){ return 1.f/(1.f+expf(-x)); }

__device__ __forceinline__ unsigned short f2bf(float f){
  unsigned int u = __float_as_uint(f);
  u += 0x7FFFu + ((u >> 16) & 1u);
  return (unsigned short)(u >> 16);
}
__device__ __forceinline__ float bf2f(unsigned int u){
  return __uint_as_float((u & 0xFFFFu) << 16);
}

// ---------------- mega prep: all input-only transforms in ONE kernel ----------------
constexpr int PW_A = DIN*Hh;            // 51200   gW0t[256][200] fp32
constexpr int PW_B = Hh*Hh;             // 65536   gW1tb
constexpr int PW_C = Hh*Hh;             // 65536   gW2tb
constexpr int PW_D = 4*Hh*Hh;           // 262144  WihRb [1024][256] = Wih[:,256:512]
constexpr int PW_E = Hh*2*Hh;           // 131072  mWb
constexpr int PW_F = 128*Hh;            // 32768   p0Wb
constexpr int PW_G = 128*128;           // 16384   p1Wb
constexpr int PW_H = Bb + 1;            // 4097    boffs
constexpr int PW_I = 4*Hh;              // 1024    bsum
constexpr int PW_TOT = PW_A+PW_B+PW_C+PW_D+PW_E+PW_F+PW_G+PW_H+PW_I;

__global__ void k_prep(const float* __restrict__ gW0, float* __restrict__ gW0t,
                       const float* __restrict__ gW1, unsigned short* __restrict__ gW1tb,
                       const float* __restrict__ gW2, unsigned short* __restrict__ gW2tb,
                       const float* __restrict__ Wih, unsigned short* __restrict__ WihRb,
                       const float* __restrict__ mW, unsigned short* __restrict__ mWb,
                       const float* __restrict__ p0W, unsigned short* __restrict__ p0Wb,
                       const float* __restrict__ p1W, unsigned short* __restrict__ p1Wb,
                       const int* __restrict__ batch, int* __restrict__ boffs,
                       const float* __restrict__ bih, const float* __restrict__ bhh,
                       float* __restrict__ bsum){
  int idx = blockIdx.x*256 + threadIdx.x;
  if (idx >= PW_TOT) return;
  if (idx < PW_A){
    int r = idx / Hh, c = idx % Hh;                 // gW0 [200][256]
    gW0t[(size_t)c*DIN + r] = gW0[idx];
    return;
  }
  idx -= PW_A;
  if (idx < PW_B){
    int r = idx >> 8, c = idx & 255;
    gW1tb[(size_t)c*Hh + r] = f2bf(gW1[idx]);
    return;
  }
  idx -= PW_B;
  if (idx < PW_C){
    int r = idx >> 8, c = idx & 255;
    gW2tb[(size_t)c*Hh + r] = f2bf(gW2[idx]);
    return;
  }
  idx -= PW_C;
  if (idx < PW_D){
    int gi = idx >> 8, k = idx & 255;
    WihRb[idx] = f2bf(Wih[(size_t)gi*2*Hh + Hh + k]);
    return;
  }
  idx -= PW_D;
  if (idx < PW_E){ mWb[idx] = f2bf(mW[idx]); return; }
  idx -= PW_E;
  if (idx < PW_F){ p0Wb[idx] = f2bf(p0W[idx]); return; }
  idx -= PW_F;
  if (idx < PW_G){ p1Wb[idx] = f2bf(p1W[idx]); return; }
  idx -= PW_G;
  if (idx < PW_H){
    int b = idx;
    int lo = 0, hi = Nn;
    while (lo < hi){ int mid = (lo+hi)>>1; if (batch[mid] < b) lo = mid+1; else hi = mid; }
    boffs[b] = lo;
    return;
  }
  idx -= PW_H;
  bsum[idx] = bih[idx] + bhh[idx];
}

// step-0 LSTM from zero state: constant across graphs
__global__ void k_h0(const float* __restrict__ bsum, float* __restrict__ h0,
                     float* __restrict__ c0){
  int ch = threadIdx.x;
  float ig = sigf(bsum[ch]);
  float gg = tanhf(bsum[2*Hh + ch]);
  float og = sigf(bsum[3*Hh + ch]);
  float cn = ig*gg;
  float hn = og*tanhf(cn);
  c0[ch] = cn; h0[ch] = hn;
}

// gconst[gi] = bsum[gi] + sum_k h0[k]*(Wih[gi][k] + Whh[gi][k]); wave per gi
__global__ void k_gconst(const float* __restrict__ Wih, const float* __restrict__ Whh,
                         const float* __restrict__ bsum, const float* __restrict__ h0,
                         float* __restrict__ gconst){
  int wid = threadIdx.x >> 6, lane = threadIdx.x & 63;
  int gi = blockIdx.x*4 + wid;
  float4 hv = ((const float4*)h0)[lane];
  float4 a = *reinterpret_cast<const float4*>(Wih + (size_t)gi*2*Hh + lane*4);
  float4 b = *reinterpret_cast<const float4*>(Whh + (size_t)gi*Hh  + lane*4);
  float ssum = hv.x*(a.x+b.x) + hv.y*(a.y+b.y) + hv.z*(a.z+b.z) + hv.w*(a.w+b.w);
  for (int off=32; off; off>>=1) ssum += __shfl_down(ssum, off, 64);
  if (lane == 0) gconst[gi] = bsum[gi] + ssum;
}

__global__ void k_count(const int* __restrict__ dst, int* __restrict__ counts){
  int e = blockIdx.x*256 + threadIdx.x;
  if (e < Ee) atomicAdd(&counts[dst[e]], 1);
}

// ---------------- hierarchical scan (3 phases; dinv folded in ph1, fptr in ph3) ----------------
__global__ void k_scan1(const int* __restrict__ counts, int* __restrict__ partial,
                        float* __restrict__ dinv){
  __shared__ int red[256];
  int t = threadIdx.x;
  int base = blockIdx.x*SCHUNK + t*4;
  int s = 0;
  if (base + 3 < Nn){
    int4 v = *reinterpret_cast<const int4*>(counts + base);
    s = v.x+v.y+v.z+v.w;
    dinv[base]   = rsqrtf((float)(v.x + 1));
    dinv[base+1] = rsqrtf((float)(v.y + 1));
    dinv[base+2] = rsqrtf((float)(v.z + 1));
    dinv[base+3] = rsqrtf((float)(v.w + 1));
  } else {
    for (int i=0;i<4;++i) if (base+i<Nn){ int c = counts[base+i]; s += c; dinv[base+i] = rsqrtf((float)(c+1)); }
  }
  red[t] = s; __syncthreads();
  for (int st=128; st>0; st>>=1){ if (t<st) red[t]+=red[t+st]; __syncthreads(); }
  if (t==0) partial[blockIdx.x] = red[0];
}

__global__ void k_scan2(int* __restrict__ partial, int n){
  __shared__ int buf[128];
  int t = threadIdx.x;
  int v = (t < n) ? partial[t] : 0;
  buf[t] = v; __syncthreads();
  for (int off=1; off<128; off<<=1){
    int tv = (t>=off) ? buf[t-off] : 0;
    __syncthreads();
    buf[t] += tv;
    __syncthreads();
  }
  if (t < n) partial[t] = buf[t] - v;
}

__global__ void k_scan3(const int* __restrict__ counts, const int* __restrict__ partial,
                        int* __restrict__ offs, int* __restrict__ fptr){
  __shared__ int red[256];
  int t = threadIdx.x;
  int base = blockIdx.x*SCHUNK + t*4;
  int c0=0,c1=0,c2=0,c3=0;
  if (base + 3 < Nn){ int4 v = *reinterpret_cast<const int4*>(counts + base); c0=v.x;c1=v.y;c2=v.z;c3=v.w; }
  else { if (base<Nn) c0=counts[base]; if (base+1<Nn) c1=counts[base+1];
         if (base+2<Nn) c2=counts[base+2]; if (base+3<Nn) c3=counts[base+3]; }
  int s = c0+c1+c2+c3;
  red[t] = s; __syncthreads();
  for (int off=1; off<256; off<<=1){
    int tv = (t>=off) ? red[t-off] : 0;
    __syncthreads();
    red[t] += tv;
    __syncthreads();
  }
  int run = partial[blockIdx.x] + red[t] - s;
  if (base   < Nn){ offs[base]   = run; fptr[base]   = run; } run += c0;
  if (base+1 < Nn){ offs[base+1] = run; fptr[base+1] = run; } run += c1;
  if (base+2 < Nn){ offs[base+2] = run; fptr[base+2] = run; } run += c2;
  if (base+3 < Nn){ offs[base+3] = run; fptr[base+3] = run; } run += c3;
  if (blockIdx.x == gridDim.x-1 && t == 255) offs[Nn] = partial[blockIdx.x] + red[255];
}

// fill packed edge list: epack[pos] = (src, bits(norm)); evoc[pos] = vocab(src)
__global__ void k_fill(const int* __restrict__ ei, const float* __restrict__ dinv,
                       const int* __restrict__ sto_x, int* __restrict__ fptr,
                       uint2* __restrict__ epack, unsigned char* __restrict__ evoc){
  int e = blockIdx.x*256 + threadIdx.x;
  if (e >= Ee) return;
  int s = ei[e], d = ei[Ee + e];
  int pos = atomicAdd(&fptr[d], 1);
  epack[pos] = make_uint2((unsigned int)s, __float_as_uint(dinv[s]*dinv[d]));
  int v = sto_x[s];
  evoc[pos] = (unsigned char)((v == 0) ? (Vv-1) : v-1);
}

// ---------------- layer 0: direct fp32 table gather (wave per node) ----------------
__global__ void k_conv0(const float* __restrict__ WG0f, const int* __restrict__ sto_x,
                        const int* __restrict__ offs, const uint2* __restrict__ epack,
                        const unsigned char* __restrict__ evoc, const float* __restrict__ dinv,
                        const float* __restrict__ bias, unsigned short* __restrict__ Xb){
  int wid = threadIdx.x >> 6, lane = threadIdx.x & 63;
  int n = blockIdx.x*4 + wid;
  const float4* Wv = (const float4*)WG0f;
  int v0 = sto_x[n]; int r0 = (v0 == 0) ? (Vv-1) : v0-1;
  float dn = dinv[n]; float s2 = dn*dn;
  float4 w0 = Wv[(size_t)r0*64 + lane];
  float a0 = w0.x*s2, a1 = w0.y*s2, a2 = w0.z*s2, a3 = w0.w*s2;
  int s = offs[n], e = offs[n+1];
  int k = s;
  for (; k + 7 < e; k += 8){
    uint2 ev[8]; int rv[8]; float4 g[8];
    #pragma unroll
    for (int j = 0; j < 8; ++j){ ev[j] = epack[k+j]; rv[j] = evoc[k+j]; }
    #pragma unroll
    for (int j = 0; j < 8; ++j) g[j] = Wv[(size_t)rv[j]*64 + lane];
    #pragma unroll
    for (int j = 0; j < 8; ++j){
      float nn = __uint_as_float(ev[j].y);
      a0 += g[j].x*nn; a1 += g[j].y*nn; a2 += g[j].z*nn; a3 += g[j].w*nn;
    }
  }
  for (; k < e; ++k){
    uint2 ev = epack[k];
    float4 g = Wv[(size_t)evoc[k]*64 + lane];
    float nn = __uint_as_float(ev.y);
    a0 += g.x*nn; a1 += g.y*nn; a2 += g.z*nn; a3 += g.w*nn;
  }
  float4 bv = ((const float4*)bias)[lane];
  a0 = fmaxf(a0 + bv.x, 0.f); a1 = fmaxf(a1 + bv.y, 0.f);
  a2 = fmaxf(a2 + bv.z, 0.f); a3 = fmaxf(a3 + bv.w, 0.f);
  uint2 o;
  o.x = (unsigned int)f2bf(a0) | ((unsigned int)f2bf(a1) << 16);
  o.y = (unsigned int)f2bf(a2) | ((unsigned int)f2bf(a3) << 16);
  ((uint2*)Xb)[(size_t)n*64 + lane] = o;
}

// ---------------- GCN aggregate (wave per node, uint2 lanes, 8-edge unroll) ----------------
__global__ void k_agg(const unsigned short* __restrict__ Xb, const int* __restrict__ offs,
                      const uint2* __restrict__ epack, const float* __restrict__ dinv,
                      unsigned short* __restrict__ T){
  int wid = threadIdx.x >> 6, lane = threadIdx.x & 63;
  int n = blockIdx.x*4 + wid;
  const uint2* Xv = (const uint2*)Xb;
  uint2 v = Xv[(size_t)n*64 + lane];
  float dn = dinv[n]; float s2 = dn*dn;
  float a0 = bf2f(v.x)*s2, a1 = bf2f(v.x>>16)*s2;
  float a2 = bf2f(v.y)*s2, a3 = bf2f(v.y>>16)*s2;
  int s = offs[n], e = offs[n+1];
  int k = s;
  for (; k + 7 < e; k += 8){
    uint2 ev[8], g[8];
    #pragma unroll
    for (int j = 0; j < 8; ++j) ev[j] = epack[k+j];
    #pragma unroll
    for (int j = 0; j < 8; ++j) g[j] = Xv[(size_t)ev[j].x*64 + lane];
    #pragma unroll
    for (int j = 0; j < 8; ++j){
      float nn = __uint_as_float(ev[j].y);
      a0 += bf2f(g[j].x)*nn; a1 += bf2f(g[j].x>>16)*nn;
      a2 += bf2f(g[j].y)*nn; a3 += bf2f(g[j].y>>16)*nn;
    }
  }
  for (; k + 1 < e; k += 2){
    uint2 e0 = epack[k], e1 = epack[k+1];
    uint2 g0 = Xv[(size_t)e0.x*64 + lane];
    uint2 g1 = Xv[(size_t)e1.x*64 + lane];
    float n0 = __uint_as_float(e0.y), n1 = __uint_as_float(e1.y);
    a0 += bf2f(g0.x)*n0; a1 += bf2f(g0.x>>16)*n0; a2 += bf2f(g0.y)*n0; a3 += bf2f(g0.y>>16)*n0;
    a0 += bf2f(g1.x)*n1; a1 += bf2f(g1.x>>16)*n1; a2 += bf2f(g1.y)*n1; a3 += bf2f(g1.y>>16)*n1;
  }
  if (k < e){
    uint2 e0 = epack[k];
    uint2 g0 = Xv[(size_t)e0.x*64 + lane];
    float n0 = __uint_as_float(e0.y);
    a0 += bf2f(g0.x)*n0; a1 += bf2f(g0.x>>16)*n0;
    a2 += bf2f(g0.y)*n0; a3 += bf2f(g0.y>>16)*n0;
  }
  uint2 o;
  o.x = (unsigned int)f2bf(a0) | ((unsigned int)f2bf(a1) << 16);
  o.y = (unsigned int)f2bf(a2) | ((unsigned int)f2bf(a3) << 16);
  ((uint2*)T)[(size_t)n*64 + lane] = o;
}

// ---------------- 8-wave bf16 MFMA NT GEMM, 64x256 tile, BK=64 ----------------
__global__ __launch_bounds__(512) void k_gemm64(
    const unsigned short* __restrict__ A, int lda,
    const unsigned short* __restrict__ Bt,
    const float* __restrict__ bias, const float* __restrict__ rowscale,
    const float* __restrict__ addf,
    float* __restrict__ Cf, unsigned short* __restrict__ Cb,
    int M, int K, int Nc, int relu)
{
  __shared__ unsigned short lds[23040];                                // 46,080 B
  unsigned short (*Al)[72] = (unsigned short(*)[72])lds;               // 64x72
  unsigned short (*Bl)[72] = (unsigned short(*)[72])(lds + 64*72);     // 256x72

  int tid = threadIdx.x;
  int w = tid >> 6, lane = tid & 63;
  int wr = (w >> 2)*32, wc = (w & 3)*64;
  int l16 = lane & 15, kh = lane >> 4;
  int rbase = blockIdx.y*64, cbase = blockIdx.x*256;
  int sr = tid >> 3, sb = tid & 7;

  f32x4 acc[2][4] = {};

  for (int k0 = 0; k0 < K; k0 += 64){
    int kk = k0 + sb*8;
    uint4 a0 = make_uint4(0,0,0,0);
    int ar = rbase + sr;
    if (ar < M) a0 = *reinterpret_cast<const uint4*>(A + (size_t)ar*lda + kk);
    uint4 b0 = *reinterpret_cast<const uint4*>(Bt + (size_t)(cbase + sr      )*K + kk);
    uint4 b1 = *reinterpret_cast<const uint4*>(Bt + (size_t)(cbase + sr +  64)*K + kk);
    uint4 b2 = *reinterpret_cast<const uint4*>(Bt + (size_t)(cbase + sr + 128)*K + kk);
    uint4 b3 = *reinterpret_cast<const uint4*>(Bt + (size_t)(cbase + sr + 192)*K + kk);
    __syncthreads();
    *reinterpret_cast<uint4*>(&Al[sr][sb*8])     = a0;
    *reinterpret_cast<uint4*>(&Bl[sr][sb*8])     = b0;
    *reinterpret_cast<uint4*>(&Bl[sr+64][sb*8])  = b1;
    *reinterpret_cast<uint4*>(&Bl[sr+128][sb*8]) = b2;
    *reinterpret_cast<uint4*>(&Bl[sr+192][sb*8]) = b3;
    __syncthreads();

    #pragma unroll
    for (int kq = 0; kq < 2; ++kq){
      short8 af[2], bfv[4];
      #pragma unroll
      for (int m = 0; m < 2; ++m)
        af[m] = *reinterpret_cast<const short8*>(&Al[wr + m*16 + l16][kq*32 + kh*8]);
      #pragma unroll
      for (int n2 = 0; n2 < 4; ++n2)
        bfv[n2] = *reinterpret_cast<const short8*>(&Bl[wc + n2*16 + l16][kq*32 + kh*8]);
      #pragma unroll
      for (int m = 0; m < 2; ++m)
        #pragma unroll
        for (int n2 = 0; n2 < 4; ++n2)
          acc[m][n2] = __builtin_amdgcn_mfma_f32_16x16x32_bf16(af[m], bfv[n2], acc[m][n2], 0, 0, 0);
    }
  }

  if (Cf){
    #pragma unroll
    for (int n2 = 0; n2 < 4; ++n2){
      int col = cbase + wc + n2*16 + l16;
      float bv = bias ? bias[col] : 0.f;
      #pragma unroll
      for (int m = 0; m < 2; ++m){
        #pragma unroll
        for (int i = 0; i < 4; ++i){
          int row = rbase + wr + m*16 + kh*4 + i;
          if (row >= M) continue;
          float v = acc[m][n2][i] + bv;
          if (addf) v += addf[(size_t)row*Nc + col];
          if (rowscale) v *= rowscale[row];
          if (relu == 1) v = fmaxf(v, 0.f);
          else if (relu == 2) v = (v > 0.f) ? v : 0.01f*v;
          Cf[(size_t)row*Nc + col] = v;
        }
      }
    }
  }
  if (Cb){
    __syncthreads();
    unsigned short* eps = lds + w*(32*72);
    #pragma unroll
    for (int n2 = 0; n2 < 4; ++n2){
      int colg = cbase + wc + n2*16 + l16;
      float bv = bias ? bias[colg] : 0.f;
      #pragma unroll
      for (int m = 0; m < 2; ++m){
        #pragma unroll
        for (int i = 0; i < 4; ++i){
          int lrow = m*16 + kh*4 + i;
          int rowg = rbase + wr + lrow;
          float v = acc[m][n2][i] + bv;
          float rs = (rowscale && rowg < M) ? rowscale[rowg] : 1.f;
          v *= rs;
          if (relu == 1) v = fmaxf(v, 0.f);
          else if (relu == 2) v = (v > 0.f) ? v : 0.01f*v;
          eps[lrow*72 + n2*16 + l16] = f2bf(v);
        }
      }
    }
    int c8 = lane & 7;
    #pragma unroll
    for (int rd = 0; rd < 4; ++rd){
      int lrow = rd*8 + (lane >> 3);
      int rowg = rbase + wr + lrow;
      short8 vv = *reinterpret_cast<const short8*>(&eps[lrow*72 + c8*8]);
      if (rowg < M)
        *reinterpret_cast<short8*>(Cb + (size_t)rowg*Nc + cbase + wc + c8*8) = vv;
    }
  }
}

// ---------------- 8-wave bf16 MFMA NT GEMM, 128x128 tile (Nc=128 GEMMs) ------------
__global__ __launch_bounds__(512) void k_gemm8(
    const unsigned short* __restrict__ A, int lda,
    const unsigned short* __restrict__ Bt,
    const float* __restrict__ bias, const float* __restrict__ rowscale,
    const float* __restrict__ addf,
    float* __restrict__ Cf, unsigned short* __restrict__ Cb,
    int M, int K, int Nc, int relu)
{
  __shared__ unsigned short lds[18432];
  unsigned short (*Al)[40] = (unsigned short(*)[40])lds;
  unsigned short (*Bl)[40] = (unsigned short(*)[40])(lds + 128*40);

  int tid = threadIdx.x;
  int w = tid >> 6, lane = tid & 63;
  int wr = (w >> 1)*32, wc = (w & 1)*64;
  int l16 = lane & 15, kh = lane >> 4;
  int rbase = blockIdx.y*128, cbase = blockIdx.x*128;
  int sr = tid >> 2, sb = tid & 3;

  f32x4 acc[2][4] = {};

  for (int k0 = 0; k0 < K; k0 += 32){
    int kk = k0 + sb*8;
    uint4 a0 = make_uint4(0,0,0,0);
    int ar0 = rbase + sr;
    if (ar0 < M) a0 = *reinterpret_cast<const uint4*>(A + (size_t)ar0*lda + kk);
    uint4 b0 = *reinterpret_cast<const uint4*>(Bt + (size_t)(cbase + sr)*K + kk);
    __syncthreads();
    *reinterpret_cast<uint4*>(&Al[sr][sb*8]) = a0;
    *reinterpret_cast<uint4*>(&Bl[sr][sb*8]) = b0;
    __syncthreads();

    short8 af[2], bfv[4];
    #pragma unroll
    for (int m = 0; m < 2; ++m) af[m] = *reinterpret_cast<const short8*>(&Al[wr + m*16 + l16][kh*8]);
    #pragma unroll
    for (int n2 = 0; n2 < 4; ++n2) bfv[n2] = *reinterpret_cast<const short8*>(&Bl[wc + n2*16 + l16][kh*8]);
    #pragma unroll
    for (int m = 0; m < 2; ++m)
      #pragma unroll
      for (int n2 = 0; n2 < 4; ++n2)
        acc[m][n2] = __builtin_amdgcn_mfma_f32_16x16x32_bf16(af[m], bfv[n2], acc[m][n2], 0, 0, 0);
  }

  if (Cf){
    #pragma unroll
    for (int n2 = 0; n2 < 4; ++n2){
      int col = cbase + wc + n2*16 + l16;
      float bv = bias ? bias[col] : 0.f;
      #pragma unroll
      for (int m = 0; m < 2; ++m){
        #pragma unroll
        for (int i = 0; i < 4; ++i){
          int row = rbase + wr + m*16 + kh*4 + i;
          if (row >= M) continue;
          float v = acc[m][n2][i] + bv;
          if (addf) v += addf[(size_t)row*Nc + col];
          if (rowscale) v *= rowscale[row];
          if (relu == 1) v = fmaxf(v, 0.f);
          else if (relu == 2) v = (v > 0.f) ? v : 0.01f*v;
          Cf[(size_t)row*Nc + col] = v;
        }
      }
    }
  }
  if (Cb){
    __syncthreads();
    unsigned short* eps = lds + w*(32*72);
    #pragma unroll
    for (int n2 = 0; n2 < 4; ++n2){
      int colg = cbase + wc + n2*16 + l16;
      float bv = bias ? bias[colg] : 0.f;
      #pragma unroll
      for (int m = 0; m < 2; ++m){
        #pragma unroll
        for (int i = 0; i < 4; ++i){
          int lrow = m*16 + kh*4 + i;
          int rowg = rbase + wr + lrow;
          float v = acc[m][n2][i] + bv;
          float rs = (rowscale && rowg < M) ? rowscale[rowg] : 1.f;
          v *= rs;
          if (relu == 1) v = fmaxf(v, 0.f);
          else if (relu == 2) v = (v > 0.f) ? v : 0.01f*v;
          eps[lrow*72 + n2*16 + l16] = f2bf(v);
        }
      }
    }
    int c8 = lane & 7;
    #pragma unroll
    for (int rd = 0; rd < 4; ++rd){
      int lrow = rd*8 + (lane >> 3);
      int rowg = rbase + wr + lrow;
      short8 vv = *reinterpret_cast<const short8*>(&eps[lrow*72 + c8*8]);
      if (rowg < M)
        *reinterpret_cast<short8*>(Cb + (size_t)rowg*Nc + cbase + wc + c8*8) = vv;
    }
  }
}

// ---------------- tiled fp32 NT GEMM (WG0 only: 103x200x256), fp32 out ----------------
__global__ __launch_bounds__(256) void k_gemm_nt(
    const float* __restrict__ A, const float* __restrict__ Bt,
    float* __restrict__ C, int M, int K, int Nc)
{
  __shared__ float As[64][20];
  __shared__ float Bs[64][20];
  int tid = threadIdx.x;
  int rbase = blockIdx.y*64, cbase = blockIdx.x*64;
  int ty = tid>>4, tx = tid&15;
  int lr = tid>>2, lq = tid&3;
  float acc[4][4] = {};
  for (int k0 = 0; k0 < K; k0 += 16){
    float4 av = make_float4(0,0,0,0), bv = make_float4(0,0,0,0);
    int kk = k0 + lq*4;
    int ar = rbase + lr;
    if (ar < M && kk < K){
      if (kk + 3 < K) av = *reinterpret_cast<const float4*>(A + (size_t)ar*K + kk);
      else { float t0[4] = {0,0,0,0}; for (int i=0; i<4 && kk+i<K; ++i) t0[i] = A[(size_t)ar*K + kk + i];
             av = make_float4(t0[0],t0[1],t0[2],t0[3]); }
    }
    int br = cbase + lr;
    if (br < Nc && kk < K){
      if (kk + 3 < K) bv = *reinterpret_cast<const float4*>(Bt + (size_t)br*K + kk);
      else { float t0[4] = {0,0,0,0}; for (int i=0; i<4 && kk+i<K; ++i) t0[i] = Bt[(size_t)br*K + kk + i];
             bv = make_float4(t0[0],t0[1],t0[2],t0[3]); }
    }
    __syncthreads();
    *reinterpret_cast<float4*>(&As[lr][lq*4]) = av;
    *reinterpret_cast<float4*>(&Bs[lr][lq*4]) = bv;
    __syncthreads();
    #pragma unroll
    for (int kc = 0; kc < 16; kc += 4){
      float4 a4[4], b4[4];
      #pragma unroll
      for (int i=0;i<4;++i) a4[i] = *reinterpret_cast<float4*>(&As[ty*4+i][kc]);
      #pragma unroll
      for (int j=0;j<4;++j) b4[j] = *reinterpret_cast<float4*>(&Bs[tx*4+j][kc]);
      #pragma unroll
      for (int i=0;i<4;++i)
        #pragma unroll
        for (int j=0;j<4;++j)
          acc[i][j] += a4[i].x*b4[j].x + a4[i].y*b4[j].y + a4[i].z*b4[j].z + a4[i].w*b4[j].w;
    }
  }
  #pragma unroll
  for (int i=0;i<4;++i){
    int r = rbase + ty*4 + i;
    if (r >= M) continue;
    #pragma unroll
    for (int j=0;j<4;++j){
      int cc = cbase + tx*4 + j;
      if (cc >= Nc) continue;
      C[(size_t)r*Nc + cc] = acc[i][j];
    }
  }
}

// ---------------- Set2Set / head ----------------
// step-1 LSTM: c from constant c0 vector; writes hbuf fp32 + qh2[.,0:256] bf16
__global__ void k_lstm1(const float* __restrict__ gates, const float* __restrict__ c0,
                        float* __restrict__ hbuf, unsigned short* __restrict__ qh2){
  int idx = blockIdx.x*256 + threadIdx.x;
  if (idx >= Bb*Hh) return;
  int b = idx >> 8, ch = idx & 255;
  const float* g = gates + (size_t)b*4*Hh;
  float ig = sigf(g[ch]);
  float fg = sigf(g[Hh + ch]);
  float gg = tanhf(g[2*Hh + ch]);
  float og = sigf(g[3*Hh + ch]);
  float cn = fg*c0[ch] + ig*gg;
  float hn = og*tanhf(cn);
  hbuf[idx] = hn;
  qh2[(size_t)b*2*Hh + ch] = f2bf(hn);
}

// fused Set2Set pool: wave per graph, online softmax (4-node chunk) + optional sto.
__global__ void k_pool(const unsigned short* __restrict__ wxb,
                       const float* __restrict__ hsrc, int hper,
                       const int* __restrict__ boffs,
                       unsigned short* __restrict__ rout, int rstride,
                       float* __restrict__ sto, int do_sto){
  int wid = threadIdx.x >> 6, lane = threadIdx.x & 63;
  int g = blockIdx.x*4 + wid;
  if (g >= Bb) return;
  const uint2* Xv = (const uint2*)wxb;
  float4 hv = hper ? ((const float4*)hsrc)[(size_t)g*64 + lane]
                   : ((const float4*)hsrc)[lane];
  int s = boffs[g], e = boffs[g+1];
  float m = -INFINITY, ssum = 0.f;
  float a0=0.f,a1=0.f,a2=0.f,a3=0.f;
  float t0=0.f,t1=0.f,t2=0.f,t3=0.f;
  int n = s;
  for (; n + 3 < e; n += 4){
    float x[4][4];
    float d[4];
    #pragma unroll
    for (int j = 0; j < 4; ++j){
      uint2 v = Xv[(size_t)(n+j)*64 + lane];
      x[j][0] = bf2f(v.x); x[j][1] = bf2f(v.x>>16);
      x[j][2] = bf2f(v.y); x[j][3] = bf2f(v.y>>16);
      d[j] = x[j][0]*hv.x + x[j][1]*hv.y + x[j][2]*hv.z + x[j][3]*hv.w;
    }
    if (do_sto){
      t0 += x[0][0]+x[1][0]+x[2][0]+x[3][0];
      t1 += x[0][1]+x[1][1]+x[2][1]+x[3][1];
      t2 += x[0][2]+x[1][2]+x[2][2]+x[3][2];
      t3 += x[0][3]+x[1][3]+x[2][3]+x[3][3];
    }
    #pragma unroll
    for (int mask=32; mask; mask>>=1){
      d[0] += __shfl_xor(d[0], mask, 64);
      d[1] += __shfl_xor(d[1], mask, 64);
      d[2] += __shfl_xor(d[2], mask, 64);
      d[3] += __shfl_xor(d[3], mask, 64);
    }
    float cmax = fmaxf(fmaxf(d[0], d[1]), fmaxf(d[2], d[3]));
    if (cmax > m){
      float sc = expf(m - cmax);          // first chunk: exp(-inf)=0 zeroes state
      ssum *= sc; a0 *= sc; a1 *= sc; a2 *= sc; a3 *= sc;
      m = cmax;
    }
    float p0e = expf(d[0]-m), p1e = expf(d[1]-m), p2e = expf(d[2]-m), p3e = expf(d[3]-m);
    ssum += p0e + p1e + p2e + p3e;
    a0 += p0e*x[0][0] + p1e*x[1][0] + p2e*x[2][0] + p3e*x[3][0];
    a1 += p0e*x[0][1] + p1e*x[1][1] + p2e*x[2][1] + p3e*x[3][1];
    a2 += p0e*x[0][2] + p1e*x[1][2] + p2e*x[2][2] + p3e*x[3][2];
    a3 += p0e*x[0][3] + p1e*x[1][3] + p2e*x[2][3] + p3e*x[3][3];
  }
  for (; n < e; ++n){
    uint2 v = Xv[(size_t)n*64 + lane];
    float x0=bf2f(v.x), x1=bf2f(v.x>>16), x2=bf2f(v.y), x3=bf2f(v.y>>16);
    if (do_sto){ t0+=x0; t1+=x1; t2+=x2; t3+=x3; }
    float d = x0*hv.x + x1*hv.y + x2*hv.z + x3*hv.w;
    #pragma unroll
    for (int mask=32; mask; mask>>=1) d += __shfl_xor(d, mask, 64);
    if (d > m){
      float sc = expf(m - d);
      ssum = ssum*sc + 1.f;
      a0 = a0*sc + x0; a1 = a1*sc + x1; a2 = a2*sc + x2; a3 = a3*sc + x3;
      m = d;
    } else {
      float p = expf(d - m);
      ssum += p; a0 += p*x0; a1 += p*x1; a2 += p*x2; a3 += p*x3;
    }
  }
  float inv = 1.f/(ssum + 1e-16f);
  uint2 o;
  o.x = (unsigned int)f2bf(a0*inv) | ((unsigned int)f2bf(a1*inv) << 16);
  o.y = (unsigned int)f2bf(a2*inv) | ((unsigned int)f2bf(a3*inv) << 16);
  ((uint2*)(rout + (size_t)g*rstride))[lane] = o;
  if (do_sto) ((float4*)sto)[(size_t)g*64 + lane] = make_float4(t0,t1,t2,t3);
}

__global__ void k_norm(float* __restrict__ mean, unsigned short* __restrict__ outb){
  __shared__ float red[256];
  int b = blockIdx.x, tid = threadIdx.x;
  float v = mean[(size_t)b*Hh + tid];
  red[tid] = v*v; __syncthreads();
  for (int st=128; st>0; st>>=1){ if (tid<st) red[tid] += red[tid+st]; __syncthreads(); }
  float nrm = fmaxf(sqrtf(red[0]), 1e-12f);
  float o = v/nrm;
  outb[(size_t)b*Hh + tid] = f2bf(o);
}

__global__ void k_out(const float* __restrict__ y1, const float* __restrict__ p2W,
                      const float* __restrict__ p2b, float* __restrict__ out){
  __shared__ float red[128];
  int b = blockIdx.x, tid = threadIdx.x;
  float v = y1[(size_t)b*128 + tid]*p2W[tid];
  red[tid] = v; __syncthreads();
  for (int st=64; st>0; st>>=1){ if (tid<st) red[tid] += red[tid+st]; __syncthreads(); }
  if (tid == 0) out[b] = red[0] + p2b[0];
}

// ---------------- launch ----------------
extern "C" void kernel_launch(void* const* d_in, const int* in_sizes, int n_in,
                              void* d_out, int out_size, void* d_ws, size_t ws_size,
                              hipStream_t stream) {
  const float* weight   = (const float*)d_in[0];
  const int*   sto_x    = (const int*)  d_in[1];
  const int*   ei       = (const int*)  d_in[2];
  const float* sto_w    = (const float*)d_in[3];
  const int*   batch    = (const int*)  d_in[4];
  const float* gW0 = (const float*)d_in[5];   const float* gb0 = (const float*)d_in[6];
  const float* gW1 = (const float*)d_in[7];   const float* gb1 = (const float*)d_in[8];
  const float* gW2 = (const float*)d_in[9];   const float* gb2 = (const float*)d_in[10];
  const float* Wih = (const float*)d_in[11];  const float* Whh = (const float*)d_in[12];
  const float* bih = (const float*)d_in[13];  const float* bhh = (const float*)d_in[14];
  const float* mW  = (const float*)d_in[15];  const float* mb  = (const float*)d_in[16];
  const float* p0W = (const float*)d_in[17];  const float* p0b = (const float*)d_in[18];
  const float* p1W = (const float*)d_in[19];  const float* p1b = (const float*)d_in[20];
  const float* p2W = (const float*)d_in[21];  const float* p2b = (const float*)d_in[22];
  float* out = (float*)d_out;

  // workspace carve (256B aligned)
  char* w = (char*)d_ws;
  auto alloc = [&](size_t bytes)->char*{ char* p = w; w += (bytes + 255) & ~size_t(255); return p; };
  unsigned short* Xb = (unsigned short*)alloc((size_t)Nn*Hh*2);
  unsigned short* Tb = (unsigned short*)alloc((size_t)Nn*Hh*2);
  float* WG0f  = (float*)alloc((size_t)Vv*Hh*4);
  float* gW0t  = (float*)alloc((size_t)Hh*DIN*4);
  unsigned short* gW1tb = (unsigned short*)alloc((size_t)Hh*Hh*2);
  unsigned short* gW2tb = (unsigned short*)alloc((size_t)Hh*Hh*2);
  unsigned short* WihRb = (unsigned short*)alloc((size_t)4*Hh*Hh*2);   // [1024][256]
  unsigned short* mWb   = (unsigned short*)alloc((size_t)Hh*2*Hh*2);
  unsigned short* p0Wb  = (unsigned short*)alloc((size_t)128*Hh*2);
  unsigned short* p1Wb  = (unsigned short*)alloc((size_t)128*128*2);
  int*   counts= (int*)  alloc((size_t)Nn*4);
  int*   offs  = (int*)  alloc((size_t)(Nn+1)*4);
  int*   fptr  = (int*)  alloc((size_t)Nn*4);
  int*   spart = (int*)  alloc((size_t)NSCAN*4);
  float* dinv  = (float*)alloc((size_t)Nn*4);
  uint2* epack = (uint2*)alloc((size_t)Ee*8);
  unsigned char* evoc = (unsigned char*)alloc((size_t)Ee);
  int*   boffs = (int*)  alloc((size_t)(Bb+1)*4);
  float* sto   = (float*)alloc((size_t)Bb*Hh*4);
  float* hbuf  = (float*)alloc((size_t)Bb*Hh*4);
  unsigned short* r0b = (unsigned short*)alloc((size_t)Bb*Hh*2);       // r (step 0)
  unsigned short* qh2 = (unsigned short*)alloc((size_t)Bb*2*Hh*2);     // [h1 | r1]
  float* gates = (float*)alloc((size_t)Bb*4*Hh*4);
  float* bsum  = (float*)alloc((size_t)4*Hh*4);
  float* h0    = (float*)alloc((size_t)Hh*4);
  float* c0    = (float*)alloc((size_t)Hh*4);
  float* gconst= (float*)alloc((size_t)4*Hh*4);
  float* meanb = (float*)alloc((size_t)Bb*Hh*4);
  unsigned short* meanbb = (unsigned short*)alloc((size_t)Bb*Hh*2);
  unsigned short* y0b = (unsigned short*)alloc((size_t)Bb*128*2);
  float* y1    = (float*)alloc((size_t)Bb*128*4);

  auto gemm8 = [&](const unsigned short* A, int lda, const unsigned short* Bt,
                   const float* bias, const float* rowscale, const float* addf,
                   float* Cf, unsigned short* Cb, int M, int K, int Nc, int relu){
    dim3 g(Nc/128, (M+127)/128);
    k_gemm8<<<g, 512, 0, stream>>>(A, lda, Bt, bias, rowscale, addf, Cf, Cb, M, K, Nc, relu);
  };
  auto gemm64 = [&](const unsigned short* A, int lda, const unsigned short* Bt,
                    const float* bias, const float* rowscale, const float* addf,
                    float* Cf, unsigned short* Cb, int M, int K, int Nc, int relu){
    dim3 g(Nc/256, (M+63)/64);
    k_gemm64<<<g, 512, 0, stream>>>(A, lda, Bt, bias, rowscale, addf, Cf, Cb, M, K, Nc, relu);
  };

  // per-launch state init (deterministic every call)
  hipMemsetAsync(counts, 0, (size_t)Nn*4, stream);

  // mega prep + LSTM step-0 constants
  k_prep<<<(PW_TOT+255)/256, 256, 0, stream>>>(
      gW0, gW0t, gW1, gW1tb, gW2, gW2tb, Wih, WihRb,
      mW, mWb, p0W, p0Wb, p1W, p1Wb, batch, boffs, bih, bhh, bsum);
  k_h0<<<1, 256, 0, stream>>>(bsum, h0, c0);
  k_gconst<<<(4*Hh)/4, 256, 0, stream>>>(Wih, Whh, bsum, h0, gconst);

  // graph structure
  k_count<<<(Ee+255)/256, 256, 0, stream>>>(ei + Ee, counts);
  k_scan1<<<NSCAN, 256, 0, stream>>>(counts, spart, dinv);
  k_scan2<<<1, 128, 0, stream>>>(spart, NSCAN);
  k_scan3<<<NSCAN, 256, 0, stream>>>(counts, spart, offs, fptr);
  k_fill<<<(Ee+255)/256, 256, 0, stream>>>(ei, dinv, sto_x, fptr, epack, evoc);

  // layer 0: WG0 = weight@gW0 (fp32 table), direct table-gather conv with bias+relu
  {
    dim3 g((Hh+63)/64, (Vv+63)/64);
    k_gemm_nt<<<g, 256, 0, stream>>>(weight, gW0t, WG0f, Vv, DIN, Hh);
  }
  k_conv0<<<Nn/4, 256, 0, stream>>>(WG0f, sto_x, offs, epack, evoc, dinv, gb0, Xb);

  // layers 1,2: aggregate, 64x256 GEMM with fused epilogue
  k_agg<<<Nn/4, 256, 0, stream>>>(Xb, offs, epack, dinv, Tb);
  gemm64(Tb, Hh, gW1tb, gb1, nullptr, nullptr, nullptr, Xb, Nn, Hh, Hh, 1);
  k_agg<<<Nn/4, 256, 0, stream>>>(Xb, offs, epack, dinv, Tb);
  gemm64(Tb, Hh, gW2tb, gb2, sto_w, nullptr, nullptr, Xb, Nn, Hh, Hh, 0);  // Xb = wx

  // Set2Set with constant-folded step 0
  k_pool<<<Bb/4, 256, 0, stream>>>(Xb, h0, 0, boffs, r0b, Hh, sto, 1);
  gemm64(r0b, Hh, WihRb, gconst, nullptr, nullptr, gates, nullptr, Bb, Hh, 4*Hh, 0);
  k_lstm1<<<(Bb*Hh+255)/256, 256, 0, stream>>>(gates, c0, hbuf, qh2);
  k_pool<<<Bb/4, 256, 0, stream>>>(Xb, hbuf, 1, boffs, qh2 + Hh, 2*Hh, nullptr, 0);

  // head: mean = [h1|r1]@mW^T + mb + sto; normalize (bf16); bf16 MLP; final dot
  gemm64(qh2, 2*Hh, mWb, mb, nullptr, sto, meanb, nullptr, Bb, 2*Hh, Hh, 0);
  k_norm<<<Bb, Hh, 0, stream>>>(meanb, meanbb);
  gemm8(meanbb, Hh, p0Wb, p0b, nullptr, nullptr, nullptr, y0b, Bb, Hh, 128, 2);
  gemm8(y0b, 128, p1Wb, p1b, nullptr, nullptr, y1, nullptr, Bb, 128, 128, 2);
  k_out<<<Bb, 128, 0, stream>>>(y1, p2W, p2b, out);
}

// Round 16
// 481.658 us; speedup vs baseline: 1.0324x; 1.0324x over previous
//
#include <hip/hip_runtime.h>
#include <math.h>

// Problem constants
constexpr int Nn  = 100000;  // nodes
constexpr int Ee  = 800000;  // edges
constexpr int Bb  = 4096;    // graphs
constexpr int Vv  = 103;     // vocab
constexpr int DIN = 200;     // embedding dim
constexpr int Hh  = 256;     // hidden

constexpr int SCHUNK = 1024;
constexpr int NSCAN  = (Nn + SCHUNK - 1)/SCHUNK;   // 98 blocks

using short8 = __attribute__((ext_vector_type(8))) short;
using f32x4  = __attribute__((ext_vector_type(4))) float;

__device__ __forceinline__ float sigf(float x){ return 1.f/(1.f+expf(-x)); }

__device__ __forceinline__ unsigned short f2bf(float f){
  unsigned int u = __float_as_uint(f);
  u += 0x7FFFu + ((u >> 16) & 1u);
  return (unsigned short)(u >> 16);
}
__device__ __forceinline__ float bf2f(unsigned int u){
  return __uint_as_float((u & 0xFFFFu) << 16);
}

// ---------------- mega prep: all input-only transforms in ONE kernel ----------------
constexpr int PW_A = DIN*Hh;            // 51200   gW0t[256][200] fp32
constexpr int PW_B = Hh*Hh;             // 65536   gW1tb
constexpr int PW_C = Hh*Hh;             // 65536   gW2tb
constexpr int PW_D = 4*Hh*Hh;           // 262144  WihRb [1024][256] = Wih[:,256:512]
constexpr int PW_E = Hh*2*Hh;           // 131072  mWb
constexpr int PW_F = 128*Hh;            // 32768   p0Wb
constexpr int PW_G = 128*128;           // 16384   p1Wb
constexpr int PW_H = Bb + 1;            // 4097    boffs
constexpr int PW_I = 4*Hh;              // 1024    bsum
constexpr int PW_TOT = PW_A+PW_B+PW_C+PW_D+PW_E+PW_F+PW_G+PW_H+PW_I;

__global__ void k_prep(const float* __restrict__ gW0, float* __restrict__ gW0t,
                       const float* __restrict__ gW1, unsigned short* __restrict__ gW1tb,
                       const float* __restrict__ gW2, unsigned short* __restrict__ gW2tb,
                       const float* __restrict__ Wih, unsigned short* __restrict__ WihRb,
                       const float* __restrict__ mW, unsigned short* __restrict__ mWb,
                       const float* __restrict__ p0W, unsigned short* __restrict__ p0Wb,
                       const float* __restrict__ p1W, unsigned short* __restrict__ p1Wb,
                       const int* __restrict__ batch, int* __restrict__ boffs,
                       const float* __restrict__ bih, const float* __restrict__ bhh,
                       float* __restrict__ bsum){
  int idx = blockIdx.x*256 + threadIdx.x;
  if (idx >= PW_TOT) return;
  if (idx < PW_A){
    int r = idx / Hh, c = idx % Hh;                 // gW0 [200][256]
    gW0t[(size_t)c*DIN + r] = gW0[idx];
    return;
  }
  idx -= PW_A;
  if (idx < PW_B){
    int r = idx >> 8, c = idx & 255;
    gW1tb[(size_t)c*Hh + r] = f2bf(gW1[idx]);
    return;
  }
  idx -= PW_B;
  if (idx < PW_C){
    int r = idx >> 8, c = idx & 255;
    gW2tb[(size_t)c*Hh + r] = f2bf(gW2[idx]);
    return;
  }
  idx -= PW_C;
  if (idx < PW_D){
    int gi = idx >> 8, k = idx & 255;
    WihRb[idx] = f2bf(Wih[(size_t)gi*2*Hh + Hh + k]);
    return;
  }
  idx -= PW_D;
  if (idx < PW_E){ mWb[idx] = f2bf(mW[idx]); return; }
  idx -= PW_E;
  if (idx < PW_F){ p0Wb[idx] = f2bf(p0W[idx]); return; }
  idx -= PW_F;
  if (idx < PW_G){ p1Wb[idx] = f2bf(p1W[idx]); return; }
  idx -= PW_G;
  if (idx < PW_H){
    int b = idx;
    int lo = 0, hi = Nn;
    while (lo < hi){ int mid = (lo+hi)>>1; if (batch[mid] < b) lo = mid+1; else hi = mid; }
    boffs[b] = lo;
    return;
  }
  idx -= PW_H;
  bsum[idx] = bih[idx] + bhh[idx];
}

// step-0 LSTM from zero state: constant across graphs
__global__ void k_h0(const float* __restrict__ bsum, float* __restrict__ h0,
                     float* __restrict__ c0){
  int ch = threadIdx.x;
  float ig = sigf(bsum[ch]);
  float gg = tanhf(bsum[2*Hh + ch]);
  float og = sigf(bsum[3*Hh + ch]);
  float cn = ig*gg;
  float hn = og*tanhf(cn);
  c0[ch] = cn; h0[ch] = hn;
}

// gconst[gi] = bsum[gi] + sum_k h0[k]*(Wih[gi][k] + Whh[gi][k]); wave per gi
__global__ void k_gconst(const float* __restrict__ Wih, const float* __restrict__ Whh,
                         const float* __restrict__ bsum, const float* __restrict__ h0,
                         float* __restrict__ gconst){
  int wid = threadIdx.x >> 6, lane = threadIdx.x & 63;
  int gi = blockIdx.x*4 + wid;
  float4 hv = ((const float4*)h0)[lane];
  float4 a = *reinterpret_cast<const float4*>(Wih + (size_t)gi*2*Hh + lane*4);
  float4 b = *reinterpret_cast<const float4*>(Whh + (size_t)gi*Hh  + lane*4);
  float ssum = hv.x*(a.x+b.x) + hv.y*(a.y+b.y) + hv.z*(a.z+b.z) + hv.w*(a.w+b.w);
  for (int off=32; off; off>>=1) ssum += __shfl_down(ssum, off, 64);
  if (lane == 0) gconst[gi] = bsum[gi] + ssum;
}

__global__ void k_count(const int* __restrict__ dst, int* __restrict__ counts){
  int e = blockIdx.x*256 + threadIdx.x;
  if (e < Ee) atomicAdd(&counts[dst[e]], 1);
}

// ---------------- hierarchical scan (3 phases; dinv folded in ph1, fptr in ph3) ----------------
__global__ void k_scan1(const int* __restrict__ counts, int* __restrict__ partial,
                        float* __restrict__ dinv){
  __shared__ int red[256];
  int t = threadIdx.x;
  int base = blockIdx.x*SCHUNK + t*4;
  int s = 0;
  if (base + 3 < Nn){
    int4 v = *reinterpret_cast<const int4*>(counts + base);
    s = v.x+v.y+v.z+v.w;
    dinv[base]   = rsqrtf((float)(v.x + 1));
    dinv[base+1] = rsqrtf((float)(v.y + 1));
    dinv[base+2] = rsqrtf((float)(v.z + 1));
    dinv[base+3] = rsqrtf((float)(v.w + 1));
  } else {
    for (int i=0;i<4;++i) if (base+i<Nn){ int c = counts[base+i]; s += c; dinv[base+i] = rsqrtf((float)(c+1)); }
  }
  red[t] = s; __syncthreads();
  for (int st=128; st>0; st>>=1){ if (t<st) red[t]+=red[t+st]; __syncthreads(); }
  if (t==0) partial[blockIdx.x] = red[0];
}

__global__ void k_scan2(int* __restrict__ partial, int n){
  __shared__ int buf[128];
  int t = threadIdx.x;
  int v = (t < n) ? partial[t] : 0;
  buf[t] = v; __syncthreads();
  for (int off=1; off<128; off<<=1){
    int tv = (t>=off) ? buf[t-off] : 0;
    __syncthreads();
    buf[t] += tv;
    __syncthreads();
  }
  if (t < n) partial[t] = buf[t] - v;
}

__global__ void k_scan3(const int* __restrict__ counts, const int* __restrict__ partial,
                        int* __restrict__ offs, int* __restrict__ fptr){
  __shared__ int red[256];
  int t = threadIdx.x;
  int base = blockIdx.x*SCHUNK + t*4;
  int c0=0,c1=0,c2=0,c3=0;
  if (base + 3 < Nn){ int4 v = *reinterpret_cast<const int4*>(counts + base); c0=v.x;c1=v.y;c2=v.z;c3=v.w; }
  else { if (base<Nn) c0=counts[base]; if (base+1<Nn) c1=counts[base+1];
         if (base+2<Nn) c2=counts[base+2]; if (base+3<Nn) c3=counts[base+3]; }
  int s = c0+c1+c2+c3;
  red[t] = s; __syncthreads();
  for (int off=1; off<256; off<<=1){
    int tv = (t>=off) ? red[t-off] : 0;
    __syncthreads();
    red[t] += tv;
    __syncthreads();
  }
  int run = partial[blockIdx.x] + red[t] - s;
  if (base   < Nn){ offs[base]   = run; fptr[base]   = run; } run += c0;
  if (base+1 < Nn){ offs[base+1] = run; fptr[base+1] = run; } run += c1;
  if (base+2 < Nn){ offs[base+2] = run; fptr[base+2] = run; } run += c2;
  if (base+3 < Nn){ offs[base+3] = run; fptr[base+3] = run; } run += c3;
  if (blockIdx.x == gridDim.x-1 && t == 255) offs[Nn] = partial[blockIdx.x] + red[255];
}

// fill packed edge list: epack[pos] = (src, bits(norm)); evoc[pos] = vocab(src)
__global__ void k_fill(const int* __restrict__ ei, const float* __restrict__ dinv,
                       const int* __restrict__ sto_x, int* __restrict__ fptr,
                       uint2* __restrict__ epack, unsigned char* __restrict__ evoc){
  int e = blockIdx.x*256 + threadIdx.x;
  if (e >= Ee) return;
  int s = ei[e], d = ei[Ee + e];
  int pos = atomicAdd(&fptr[d], 1);
  epack[pos] = make_uint2((unsigned int)s, __float_as_uint(dinv[s]*dinv[d]));
  int v = sto_x[s];
  evoc[pos] = (unsigned char)((v == 0) ? (Vv-1) : v-1);
}

// ---------------- layer 0: bf16 table gather (half-wave uint4, wave per node) ----------------
__global__ void k_conv0(const unsigned short* __restrict__ WG0b, const int* __restrict__ sto_x,
                        const int* __restrict__ offs, const uint2* __restrict__ epack,
                        const unsigned char* __restrict__ evoc, const float* __restrict__ dinv,
                        const float* __restrict__ bias, unsigned short* __restrict__ Xb){
  int wid = threadIdx.x >> 6, lane = threadIdx.x & 63;
  int half = lane >> 5, l32 = lane & 31;
  int n = blockIdx.x*4 + wid;
  const uint4* Wv = (const uint4*)WG0b;   // table row = 32 x 16B
  float a0=0.f,a1=0.f,a2=0.f,a3=0.f,a4=0.f,a5=0.f,a6=0.f,a7=0.f;
  if (half == 0){
    int v0 = sto_x[n]; int r0 = (v0 == 0) ? (Vv-1) : v0-1;
    float dn = dinv[n]; float s2 = dn*dn;
    uint4 w = Wv[(size_t)r0*32 + l32];
    a0 = bf2f(w.x)*s2; a1 = bf2f(w.x>>16)*s2;
    a2 = bf2f(w.y)*s2; a3 = bf2f(w.y>>16)*s2;
    a4 = bf2f(w.z)*s2; a5 = bf2f(w.z>>16)*s2;
    a6 = bf2f(w.w)*s2; a7 = bf2f(w.w>>16)*s2;
  }
  int s = offs[n], e = offs[n+1];
  int k = s + half;
  for (; k + 6 < e; k += 8){
    uint2 ev[4]; int rv[4]; uint4 g[4];
    #pragma unroll
    for (int j = 0; j < 4; ++j){ ev[j] = epack[k+2*j]; rv[j] = evoc[k+2*j]; }
    #pragma unroll
    for (int j = 0; j < 4; ++j) g[j] = Wv[(size_t)rv[j]*32 + l32];
    #pragma unroll
    for (int j = 0; j < 4; ++j){
      float nn = __uint_as_float(ev[j].y);
      a0 += bf2f(g[j].x)*nn; a1 += bf2f(g[j].x>>16)*nn;
      a2 += bf2f(g[j].y)*nn; a3 += bf2f(g[j].y>>16)*nn;
      a4 += bf2f(g[j].z)*nn; a5 += bf2f(g[j].z>>16)*nn;
      a6 += bf2f(g[j].w)*nn; a7 += bf2f(g[j].w>>16)*nn;
    }
  }
  for (; k < e; k += 2){
    uint2 ev = epack[k];
    uint4 g = Wv[(size_t)evoc[k]*32 + l32];
    float nn = __uint_as_float(ev.y);
    a0 += bf2f(g.x)*nn; a1 += bf2f(g.x>>16)*nn;
    a2 += bf2f(g.y)*nn; a3 += bf2f(g.y>>16)*nn;
    a4 += bf2f(g.z)*nn; a5 += bf2f(g.z>>16)*nn;
    a6 += bf2f(g.w)*nn; a7 += bf2f(g.w>>16)*nn;
  }
  a0 += __shfl_xor(a0, 32, 64); a1 += __shfl_xor(a1, 32, 64);
  a2 += __shfl_xor(a2, 32, 64); a3 += __shfl_xor(a3, 32, 64);
  a4 += __shfl_xor(a4, 32, 64); a5 += __shfl_xor(a5, 32, 64);
  a6 += __shfl_xor(a6, 32, 64); a7 += __shfl_xor(a7, 32, 64);
  if (half == 0){
    float4 b0 = ((const float4*)bias)[l32*2];
    float4 b1 = ((const float4*)bias)[l32*2+1];
    a0 = fmaxf(a0 + b0.x, 0.f); a1 = fmaxf(a1 + b0.y, 0.f);
    a2 = fmaxf(a2 + b0.z, 0.f); a3 = fmaxf(a3 + b0.w, 0.f);
    a4 = fmaxf(a4 + b1.x, 0.f); a5 = fmaxf(a5 + b1.y, 0.f);
    a6 = fmaxf(a6 + b1.z, 0.f); a7 = fmaxf(a7 + b1.w, 0.f);
    uint4 o;
    o.x = (unsigned int)f2bf(a0) | ((unsigned int)f2bf(a1) << 16);
    o.y = (unsigned int)f2bf(a2) | ((unsigned int)f2bf(a3) << 16);
    o.z = (unsigned int)f2bf(a4) | ((unsigned int)f2bf(a5) << 16);
    o.w = (unsigned int)f2bf(a6) | ((unsigned int)f2bf(a7) << 16);
    ((uint4*)Xb)[(size_t)n*32 + l32] = o;
  }
}

// ---------------- GCN aggregate (half-wave uint4 gathers, wave per node) ----------------
__global__ void k_agg(const unsigned short* __restrict__ Xb, const int* __restrict__ offs,
                      const uint2* __restrict__ epack, const float* __restrict__ dinv,
                      unsigned short* __restrict__ T){
  int wid = threadIdx.x >> 6, lane = threadIdx.x & 63;
  int half = lane >> 5, l32 = lane & 31;
  int n = blockIdx.x*4 + wid;
  const uint4* Xv = (const uint4*)Xb;     // row = 32 x 16B
  float a0=0.f,a1=0.f,a2=0.f,a3=0.f,a4=0.f,a5=0.f,a6=0.f,a7=0.f;
  if (half == 0){
    float dn = dinv[n]; float s2 = dn*dn;
    uint4 v = Xv[(size_t)n*32 + l32];
    a0 = bf2f(v.x)*s2; a1 = bf2f(v.x>>16)*s2;
    a2 = bf2f(v.y)*s2; a3 = bf2f(v.y>>16)*s2;
    a4 = bf2f(v.z)*s2; a5 = bf2f(v.z>>16)*s2;
    a6 = bf2f(v.w)*s2; a7 = bf2f(v.w>>16)*s2;
  }
  int s = offs[n], e = offs[n+1];
  int k = s + half;
  for (; k + 6 < e; k += 8){
    uint2 ev[4]; uint4 g[4];
    #pragma unroll
    for (int j = 0; j < 4; ++j) ev[j] = epack[k+2*j];
    #pragma unroll
    for (int j = 0; j < 4; ++j) g[j] = Xv[(size_t)ev[j].x*32 + l32];
    #pragma unroll
    for (int j = 0; j < 4; ++j){
      float nn = __uint_as_float(ev[j].y);
      a0 += bf2f(g[j].x)*nn; a1 += bf2f(g[j].x>>16)*nn;
      a2 += bf2f(g[j].y)*nn; a3 += bf2f(g[j].y>>16)*nn;
      a4 += bf2f(g[j].z)*nn; a5 += bf2f(g[j].z>>16)*nn;
      a6 += bf2f(g[j].w)*nn; a7 += bf2f(g[j].w>>16)*nn;
    }
  }
  for (; k < e; k += 2){
    uint2 ev = epack[k];
    uint4 g = Xv[(size_t)ev.x*32 + l32];
    float nn = __uint_as_float(ev.y);
    a0 += bf2f(g.x)*nn; a1 += bf2f(g.x>>16)*nn;
    a2 += bf2f(g.y)*nn; a3 += bf2f(g.y>>16)*nn;
    a4 += bf2f(g.z)*nn; a5 += bf2f(g.z>>16)*nn;
    a6 += bf2f(g.w)*nn; a7 += bf2f(g.w>>16)*nn;
  }
  a0 += __shfl_xor(a0, 32, 64); a1 += __shfl_xor(a1, 32, 64);
  a2 += __shfl_xor(a2, 32, 64); a3 += __shfl_xor(a3, 32, 64);
  a4 += __shfl_xor(a4, 32, 64); a5 += __shfl_xor(a5, 32, 64);
  a6 += __shfl_xor(a6, 32, 64); a7 += __shfl_xor(a7, 32, 64);
  if (half == 0){
    uint4 o;
    o.x = (unsigned int)f2bf(a0) | ((unsigned int)f2bf(a1) << 16);
    o.y = (unsigned int)f2bf(a2) | ((unsigned int)f2bf(a3) << 16);
    o.z = (unsigned int)f2bf(a4) | ((unsigned int)f2bf(a5) << 16);
    o.w = (unsigned int)f2bf(a6) | ((unsigned int)f2bf(a7) << 16);
    ((uint4*)T)[(size_t)n*32 + l32] = o;
  }
}

// ---------------- 8-wave bf16 MFMA NT GEMM, 64x256 tile, BK=64 ----------------
__global__ __launch_bounds__(512) void k_gemm64(
    const unsigned short* __restrict__ A, int lda,
    const unsigned short* __restrict__ Bt,
    const float* __restrict__ bias, const float* __restrict__ rowscale,
    const float* __restrict__ addf,
    float* __restrict__ Cf, unsigned short* __restrict__ Cb,
    int M, int K, int Nc, int relu)
{
  __shared__ unsigned short lds[23040];                                // 46,080 B
  unsigned short (*Al)[72] = (unsigned short(*)[72])lds;               // 64x72
  unsigned short (*Bl)[72] = (unsigned short(*)[72])(lds + 64*72);     // 256x72

  int tid = threadIdx.x;
  int w = tid >> 6, lane = tid & 63;
  int wr = (w >> 2)*32, wc = (w & 3)*64;
  int l16 = lane & 15, kh = lane >> 4;
  int rbase = blockIdx.y*64, cbase = blockIdx.x*256;
  int sr = tid >> 3, sb = tid & 7;

  f32x4 acc[2][4] = {};

  for (int k0 = 0; k0 < K; k0 += 64){
    int kk = k0 + sb*8;
    uint4 a0 = make_uint4(0,0,0,0);
    int ar = rbase + sr;
    if (ar < M) a0 = *reinterpret_cast<const uint4*>(A + (size_t)ar*lda + kk);
    uint4 b0 = *reinterpret_cast<const uint4*>(Bt + (size_t)(cbase + sr      )*K + kk);
    uint4 b1 = *reinterpret_cast<const uint4*>(Bt + (size_t)(cbase + sr +  64)*K + kk);
    uint4 b2 = *reinterpret_cast<const uint4*>(Bt + (size_t)(cbase + sr + 128)*K + kk);
    uint4 b3 = *reinterpret_cast<const uint4*>(Bt + (size_t)(cbase + sr + 192)*K + kk);
    __syncthreads();
    *reinterpret_cast<uint4*>(&Al[sr][sb*8])     = a0;
    *reinterpret_cast<uint4*>(&Bl[sr][sb*8])     = b0;
    *reinterpret_cast<uint4*>(&Bl[sr+64][sb*8])  = b1;
    *reinterpret_cast<uint4*>(&Bl[sr+128][sb*8]) = b2;
    *reinterpret_cast<uint4*>(&Bl[sr+192][sb*8]) = b3;
    __syncthreads();

    #pragma unroll
    for (int kq = 0; kq < 2; ++kq){
      short8 af[2], bfv[4];
      #pragma unroll
      for (int m = 0; m < 2; ++m)
        af[m] = *reinterpret_cast<const short8*>(&Al[wr + m*16 + l16][kq*32 + kh*8]);
      #pragma unroll
      for (int n2 = 0; n2 < 4; ++n2)
        bfv[n2] = *reinterpret_cast<const short8*>(&Bl[wc + n2*16 + l16][kq*32 + kh*8]);
      #pragma unroll
      for (int m = 0; m < 2; ++m)
        #pragma unroll
        for (int n2 = 0; n2 < 4; ++n2)
          acc[m][n2] = __builtin_amdgcn_mfma_f32_16x16x32_bf16(af[m], bfv[n2], acc[m][n2], 0, 0, 0);
    }
  }

  if (Cf){
    #pragma unroll
    for (int n2 = 0; n2 < 4; ++n2){
      int col = cbase + wc + n2*16 + l16;
      float bv = bias ? bias[col] : 0.f;
      #pragma unroll
      for (int m = 0; m < 2; ++m){
        #pragma unroll
        for (int i = 0; i < 4; ++i){
          int row = rbase + wr + m*16 + kh*4 + i;
          if (row >= M) continue;
          float v = acc[m][n2][i] + bv;
          if (addf) v += addf[(size_t)row*Nc + col];
          if (rowscale) v *= rowscale[row];
          if (relu == 1) v = fmaxf(v, 0.f);
          else if (relu == 2) v = (v > 0.f) ? v : 0.01f*v;
          Cf[(size_t)row*Nc + col] = v;
        }
      }
    }
  }
  if (Cb){
    __syncthreads();
    unsigned short* eps = lds + w*(32*72);
    #pragma unroll
    for (int n2 = 0; n2 < 4; ++n2){
      int colg = cbase + wc + n2*16 + l16;
      float bv = bias ? bias[colg] : 0.f;
      #pragma unroll
      for (int m = 0; m < 2; ++m){
        #pragma unroll
        for (int i = 0; i < 4; ++i){
          int lrow = m*16 + kh*4 + i;
          int rowg = rbase + wr + lrow;
          float v = acc[m][n2][i] + bv;
          float rs = (rowscale && rowg < M) ? rowscale[rowg] : 1.f;
          v *= rs;
          if (relu == 1) v = fmaxf(v, 0.f);
          else if (relu == 2) v = (v > 0.f) ? v : 0.01f*v;
          eps[lrow*72 + n2*16 + l16] = f2bf(v);
        }
      }
    }
    int c8 = lane & 7;
    #pragma unroll
    for (int rd = 0; rd < 4; ++rd){
      int lrow = rd*8 + (lane >> 3);
      int rowg = rbase + wr + lrow;
      short8 vv = *reinterpret_cast<const short8*>(&eps[lrow*72 + c8*8]);
      if (rowg < M)
        *reinterpret_cast<short8*>(Cb + (size_t)rowg*Nc + cbase + wc + c8*8) = vv;
    }
  }
}

// ---------------- 8-wave bf16 MFMA NT GEMM, 128x128 tile (Nc=128 GEMMs) ------------
__global__ __launch_bounds__(512) void k_gemm8(
    const unsigned short* __restrict__ A, int lda,
    const unsigned short* __restrict__ Bt,
    const float* __restrict__ bias, const float* __restrict__ rowscale,
    const float* __restrict__ addf,
    float* __restrict__ Cf, unsigned short* __restrict__ Cb,
    int M, int K, int Nc, int relu)
{
  __shared__ unsigned short lds[18432];
  unsigned short (*Al)[40] = (unsigned short(*)[40])lds;
  unsigned short (*Bl)[40] = (unsigned short(*)[40])(lds + 128*40);

  int tid = threadIdx.x;
  int w = tid >> 6, lane = tid & 63;
  int wr = (w >> 1)*32, wc = (w & 1)*64;
  int l16 = lane & 15, kh = lane >> 4;
  int rbase = blockIdx.y*128, cbase = blockIdx.x*128;
  int sr = tid >> 2, sb = tid & 3;

  f32x4 acc[2][4] = {};

  for (int k0 = 0; k0 < K; k0 += 32){
    int kk = k0 + sb*8;
    uint4 a0 = make_uint4(0,0,0,0);
    int ar0 = rbase + sr;
    if (ar0 < M) a0 = *reinterpret_cast<const uint4*>(A + (size_t)ar0*lda + kk);
    uint4 b0 = *reinterpret_cast<const uint4*>(Bt + (size_t)(cbase + sr)*K + kk);
    __syncthreads();
    *reinterpret_cast<uint4*>(&Al[sr][sb*8]) = a0;
    *reinterpret_cast<uint4*>(&Bl[sr][sb*8]) = b0;
    __syncthreads();

    short8 af[2], bfv[4];
    #pragma unroll
    for (int m = 0; m < 2; ++m) af[m] = *reinterpret_cast<const short8*>(&Al[wr + m*16 + l16][kh*8]);
    #pragma unroll
    for (int n2 = 0; n2 < 4; ++n2) bfv[n2] = *reinterpret_cast<const short8*>(&Bl[wc + n2*16 + l16][kh*8]);
    #pragma unroll
    for (int m = 0; m < 2; ++m)
      #pragma unroll
      for (int n2 = 0; n2 < 4; ++n2)
        acc[m][n2] = __builtin_amdgcn_mfma_f32_16x16x32_bf16(af[m], bfv[n2], acc[m][n2], 0, 0, 0);
  }

  if (Cf){
    #pragma unroll
    for (int n2 = 0; n2 < 4; ++n2){
      int col = cbase + wc + n2*16 + l16;
      float bv = bias ? bias[col] : 0.f;
      #pragma unroll
      for (int m = 0; m < 2; ++m){
        #pragma unroll
        for (int i = 0; i < 4; ++i){
          int row = rbase + wr + m*16 + kh*4 + i;
          if (row >= M) continue;
          float v = acc[m][n2][i] + bv;
          if (addf) v += addf[(size_t)row*Nc + col];
          if (rowscale) v *= rowscale[row];
          if (relu == 1) v = fmaxf(v, 0.f);
          else if (relu == 2) v = (v > 0.f) ? v : 0.01f*v;
          Cf[(size_t)row*Nc + col] = v;
        }
      }
    }
  }
  if (Cb){
    __syncthreads();
    unsigned short* eps = lds + w*(32*72);
    #pragma unroll
    for (int n2 = 0; n2 < 4; ++n2){
      int colg = cbase + wc + n2*16 + l16;
      float bv = bias ? bias[colg] : 0.f;
      #pragma unroll
      for (int m = 0; m < 2; ++m){
        #pragma unroll
        for (int i = 0; i < 4; ++i){
          int lrow = m*16 + kh*4 + i;
          int rowg = rbase + wr + lrow;
          float v = acc[m][n2][i] + bv;
          float rs = (rowscale && rowg < M) ? rowscale[rowg] : 1.f;
          v *= rs;
          if (relu == 1) v = fmaxf(v, 0.f);
          else if (relu == 2) v = (v > 0.f) ? v : 0.01f*v;
          eps[lrow*72 + n2*16 + l16] = f2bf(v);
        }
      }
    }
    int c8 = lane & 7;
    #pragma unroll
    for (int rd = 0; rd < 4; ++rd){
      int lrow = rd*8 + (lane >> 3);
      int rowg = rbase + wr + lrow;
      short8 vv = *reinterpret_cast<const short8*>(&eps[lrow*72 + c8*8]);
      if (rowg < M)
        *reinterpret_cast<short8*>(Cb + (size_t)rowg*Nc + cbase + wc + c8*8) = vv;
    }
  }
}

// ---------------- tiled fp32 NT GEMM (WG0 only: 103x200x256), bf16 out ----------------
__global__ __launch_bounds__(256) void k_gemm_nt(
    const float* __restrict__ A, const float* __restrict__ Bt,
    unsigned short* __restrict__ Cb, int M, int K, int Nc)
{
  __shared__ float As[64][20];
  __shared__ float Bs[64][20];
  int tid = threadIdx.x;
  int rbase = blockIdx.y*64, cbase = blockIdx.x*64;
  int ty = tid>>4, tx = tid&15;
  int lr = tid>>2, lq = tid&3;
  float acc[4][4] = {};
  for (int k0 = 0; k0 < K; k0 += 16){
    float4 av = make_float4(0,0,0,0), bv = make_float4(0,0,0,0);
    int kk = k0 + lq*4;
    int ar = rbase + lr;
    if (ar < M && kk < K){
      if (kk + 3 < K) av = *reinterpret_cast<const float4*>(A + (size_t)ar*K + kk);
      else { float t0[4] = {0,0,0,0}; for (int i=0; i<4 && kk+i<K; ++i) t0[i] = A[(size_t)ar*K + kk + i];
             av = make_float4(t0[0],t0[1],t0[2],t0[3]); }
    }
    int br = cbase + lr;
    if (br < Nc && kk < K){
      if (kk + 3 < K) bv = *reinterpret_cast<const float4*>(Bt + (size_t)br*K + kk);
      else { float t0[4] = {0,0,0,0}; for (int i=0; i<4 && kk+i<K; ++i) t0[i] = Bt[(size_t)br*K + kk + i];
             bv = make_float4(t0[0],t0[1],t0[2],t0[3]); }
    }
    __syncthreads();
    *reinterpret_cast<float4*>(&As[lr][lq*4]) = av;
    *reinterpret_cast<float4*>(&Bs[lr][lq*4]) = bv;
    __syncthreads();
    #pragma unroll
    for (int kc = 0; kc < 16; kc += 4){
      float4 a4[4], b4[4];
      #pragma unroll
      for (int i=0;i<4;++i) a4[i] = *reinterpret_cast<float4*>(&As[ty*4+i][kc]);
      #pragma unroll
      for (int j=0;j<4;++j) b4[j] = *reinterpret_cast<float4*>(&Bs[tx*4+j][kc]);
      #pragma unroll
      for (int i=0;i<4;++i)
        #pragma unroll
        for (int j=0;j<4;++j)
          acc[i][j] += a4[i].x*b4[j].x + a4[i].y*b4[j].y + a4[i].z*b4[j].z + a4[i].w*b4[j].w;
    }
  }
  #pragma unroll
  for (int i=0;i<4;++i){
    int r = rbase + ty*4 + i;
    if (r >= M) continue;
    #pragma unroll
    for (int j=0;j<4;++j){
      int cc = cbase + tx*4 + j;
      if (cc >= Nc) continue;
      Cb[(size_t)r*Nc + cc] = f2bf(acc[i][j]);
    }
  }
}

// ---------------- Set2Set / head ----------------
// step-1 LSTM: c from constant c0 vector; writes hbuf fp32 + qh2[.,0:256] bf16
__global__ void k_lstm1(const float* __restrict__ gates, const float* __restrict__ c0,
                        float* __restrict__ hbuf, unsigned short* __restrict__ qh2){
  int idx = blockIdx.x*256 + threadIdx.x;
  if (idx >= Bb*Hh) return;
  int b = idx >> 8, ch = idx & 255;
  const float* g = gates + (size_t)b*4*Hh;
  float ig = sigf(g[ch]);
  float fg = sigf(g[Hh + ch]);
  float gg = tanhf(g[2*Hh + ch]);
  float og = sigf(g[3*Hh + ch]);
  float cn = fg*c0[ch] + ig*gg;
  float hn = og*tanhf(cn);
  hbuf[idx] = hn;
  qh2[(size_t)b*2*Hh + ch] = f2bf(hn);
}

// fused Set2Set pool: wave per graph, online softmax (2-node unroll) + optional sto.
__global__ void k_pool(const unsigned short* __restrict__ wxb,
                       const float* __restrict__ hsrc, int hper,
                       const int* __restrict__ boffs,
                       unsigned short* __restrict__ rout, int rstride,
                       float* __restrict__ sto, int do_sto){
  int wid = threadIdx.x >> 6, lane = threadIdx.x & 63;
  int g = blockIdx.x*4 + wid;
  if (g >= Bb) return;
  const uint2* Xv = (const uint2*)wxb;
  float4 hv = hper ? ((const float4*)hsrc)[(size_t)g*64 + lane]
                   : ((const float4*)hsrc)[lane];
  int s = boffs[g], e = boffs[g+1];
  float m = -INFINITY, ssum = 0.f;
  float a0=0.f,a1=0.f,a2=0.f,a3=0.f;
  float t0=0.f,t1=0.f,t2=0.f,t3=0.f;
  int n = s;
  for (; n + 1 < e; n += 2){
    uint2 v0 = Xv[(size_t)n*64 + lane];
    uint2 v1 = Xv[(size_t)(n+1)*64 + lane];
    float x00=bf2f(v0.x), x01=bf2f(v0.x>>16), x02=bf2f(v0.y), x03=bf2f(v0.y>>16);
    float x10=bf2f(v1.x), x11=bf2f(v1.x>>16), x12=bf2f(v1.y), x13=bf2f(v1.y>>16);
    if (do_sto){ t0+=x00+x10; t1+=x01+x11; t2+=x02+x12; t3+=x03+x13; }
    float d0 = x00*hv.x + x01*hv.y + x02*hv.z + x03*hv.w;
    float d1 = x10*hv.x + x11*hv.y + x12*hv.z + x13*hv.w;
    #pragma unroll
    for (int mask=32; mask; mask>>=1){
      d0 += __shfl_xor(d0, mask, 64);
      d1 += __shfl_xor(d1, mask, 64);
    }
    if (d0 > m){
      float sc = expf(m - d0);
      ssum = ssum*sc + 1.f;
      a0 = a0*sc + x00; a1 = a1*sc + x01; a2 = a2*sc + x02; a3 = a3*sc + x03;
      m = d0;
    } else {
      float p = expf(d0 - m);
      ssum += p; a0 += p*x00; a1 += p*x01; a2 += p*x02; a3 += p*x03;
    }
    if (d1 > m){
      float sc = expf(m - d1);
      ssum = ssum*sc + 1.f;
      a0 = a0*sc + x10; a1 = a1*sc + x11; a2 = a2*sc + x12; a3 = a3*sc + x13;
      m = d1;
    } else {
      float p = expf(d1 - m);
      ssum += p; a0 += p*x10; a1 += p*x11; a2 += p*x12; a3 += p*x13;
    }
  }
  if (n < e){
    uint2 v0 = Xv[(size_t)n*64 + lane];
    float x00=bf2f(v0.x), x01=bf2f(v0.x>>16), x02=bf2f(v0.y), x03=bf2f(v0.y>>16);
    if (do_sto){ t0+=x00; t1+=x01; t2+=x02; t3+=x03; }
    float d0 = x00*hv.x + x01*hv.y + x02*hv.z + x03*hv.w;
    #pragma unroll
    for (int mask=32; mask; mask>>=1) d0 += __shfl_xor(d0, mask, 64);
    if (d0 > m){
      float sc = expf(m - d0);
      ssum = ssum*sc + 1.f;
      a0 = a0*sc + x00; a1 = a1*sc + x01; a2 = a2*sc + x02; a3 = a3*sc + x03;
      m = d0;
    } else {
      float p = expf(d0 - m);
      ssum += p; a0 += p*x00; a1 += p*x01; a2 += p*x02; a3 += p*x03;
    }
  }
  float inv = 1.f/(ssum + 1e-16f);
  uint2 o;
  o.x = (unsigned int)f2bf(a0*inv) | ((unsigned int)f2bf(a1*inv) << 16);
  o.y = (unsigned int)f2bf(a2*inv) | ((unsigned int)f2bf(a3*inv) << 16);
  ((uint2*)(rout + (size_t)g*rstride))[lane] = o;
  if (do_sto) ((float4*)sto)[(size_t)g*64 + lane] = make_float4(t0,t1,t2,t3);
}

__global__ void k_norm(float* __restrict__ mean, unsigned short* __restrict__ outb){
  __shared__ float red[256];
  int b = blockIdx.x, tid = threadIdx.x;
  float v = mean[(size_t)b*Hh + tid];
  red[tid] = v*v; __syncthreads();
  for (int st=128; st>0; st>>=1){ if (tid<st) red[tid] += red[tid+st]; __syncthreads(); }
  float nrm = fmaxf(sqrtf(red[0]), 1e-12f);
  float o = v/nrm;
  outb[(size_t)b*Hh + tid] = f2bf(o);
}

__global__ void k_out(const float* __restrict__ y1, const float* __restrict__ p2W,
                      const float* __restrict__ p2b, float* __restrict__ out){
  __shared__ float red[128];
  int b = blockIdx.x, tid = threadIdx.x;
  float v = y1[(size_t)b*128 + tid]*p2W[tid];
  red[tid] = v; __syncthreads();
  for (int st=64; st>0; st>>=1){ if (tid<st) red[tid] += red[tid+st]; __syncthreads(); }
  if (tid == 0) out[b] = red[0] + p2b[0];
}

// ---------------- launch ----------------
extern "C" void kernel_launch(void* const* d_in, const int* in_sizes, int n_in,
                              void* d_out, int out_size, void* d_ws, size_t ws_size,
                              hipStream_t stream) {
  const float* weight   = (const float*)d_in[0];
  const int*   sto_x    = (const int*)  d_in[1];
  const int*   ei       = (const int*)  d_in[2];
  const float* sto_w    = (const float*)d_in[3];
  const int*   batch    = (const int*)  d_in[4];
  const float* gW0 = (const float*)d_in[5];   const float* gb0 = (const float*)d_in[6];
  const float* gW1 = (const float*)d_in[7];   const float* gb1 = (const float*)d_in[8];
  const float* gW2 = (const float*)d_in[9];   const float* gb2 = (const float*)d_in[10];
  const float* Wih = (const float*)d_in[11];  const float* Whh = (const float*)d_in[12];
  const float* bih = (const float*)d_in[13];  const float* bhh = (const float*)d_in[14];
  const float* mW  = (const float*)d_in[15];  const float* mb  = (const float*)d_in[16];
  const float* p0W = (const float*)d_in[17];  const float* p0b = (const float*)d_in[18];
  const float* p1W = (const float*)d_in[19];  const float* p1b = (const float*)d_in[20];
  const float* p2W = (const float*)d_in[21];  const float* p2b = (const float*)d_in[22];
  float* out = (float*)d_out;

  // workspace carve (256B aligned)
  char* w = (char*)d_ws;
  auto alloc = [&](size_t bytes)->char*{ char* p = w; w += (bytes + 255) & ~size_t(255); return p; };
  unsigned short* Xb = (unsigned short*)alloc((size_t)Nn*Hh*2);
  unsigned short* Tb = (unsigned short*)alloc((size_t)Nn*Hh*2);
  unsigned short* WG0b = (unsigned short*)alloc((size_t)Vv*Hh*2);
  float* gW0t  = (float*)alloc((size_t)Hh*DIN*4);
  unsigned short* gW1tb = (unsigned short*)alloc((size_t)Hh*Hh*2);
  unsigned short* gW2tb = (unsigned short*)alloc((size_t)Hh*Hh*2);
  unsigned short* WihRb = (unsigned short*)alloc((size_t)4*Hh*Hh*2);   // [1024][256]
  unsigned short* mWb   = (unsigned short*)alloc((size_t)Hh*2*Hh*2);
  unsigned short* p0Wb  = (unsigned short*)alloc((size_t)128*Hh*2);
  unsigned short* p1Wb  = (unsigned short*)alloc((size_t)128*128*2);
  int*   counts= (int*)  alloc((size_t)Nn*4);
  int*   offs  = (int*)  alloc((size_t)(Nn+1)*4);
  int*   fptr  = (int*)  alloc((size_t)Nn*4);
  int*   spart = (int*)  alloc((size_t)NSCAN*4);
  float* dinv  = (float*)alloc((size_t)Nn*4);
  uint2* epack = (uint2*)alloc((size_t)Ee*8);
  unsigned char* evoc = (unsigned char*)alloc((size_t)Ee);
  int*   boffs = (int*)  alloc((size_t)(Bb+1)*4);
  float* sto   = (float*)alloc((size_t)Bb*Hh*4);
  float* hbuf  = (float*)alloc((size_t)Bb*Hh*4);
  unsigned short* r0b = (unsigned short*)alloc((size_t)Bb*Hh*2);       // r (step 0)
  unsigned short* qh2 = (unsigned short*)alloc((size_t)Bb*2*Hh*2);     // [h1 | r1]
  float* gates = (float*)alloc((size_t)Bb*4*Hh*4);
  float* bsum  = (float*)alloc((size_t)4*Hh*4);
  float* h0    = (float*)alloc((size_t)Hh*4);
  float* c0    = (float*)alloc((size_t)Hh*4);
  float* gconst= (float*)alloc((size_t)4*Hh*4);
  float* meanb = (float*)alloc((size_t)Bb*Hh*4);
  unsigned short* meanbb = (unsigned short*)alloc((size_t)Bb*Hh*2);
  unsigned short* y0b = (unsigned short*)alloc((size_t)Bb*128*2);
  float* y1    = (float*)alloc((size_t)Bb*128*4);

  auto gemm8 = [&](const unsigned short* A, int lda, const unsigned short* Bt,
                   const float* bias, const float* rowscale, const float* addf,
                   float* Cf, unsigned short* Cb, int M, int K, int Nc, int relu){
    dim3 g(Nc/128, (M+127)/128);
    k_gemm8<<<g, 512, 0, stream>>>(A, lda, Bt, bias, rowscale, addf, Cf, Cb, M, K, Nc, relu);
  };
  auto gemm64 = [&](const unsigned short* A, int lda, const unsigned short* Bt,
                    const float* bias, const float* rowscale, const float* addf,
                    float* Cf, unsigned short* Cb, int M, int K, int Nc, int relu){
    dim3 g(Nc/256, (M+63)/64);
    k_gemm64<<<g, 512, 0, stream>>>(A, lda, Bt, bias, rowscale, addf, Cf, Cb, M, K, Nc, relu);
  };

  // per-launch state init (deterministic every call)
  hipMemsetAsync(counts, 0, (size_t)Nn*4, stream);

  // mega prep + LSTM step-0 constants
  k_prep<<<(PW_TOT+255)/256, 256, 0, stream>>>(
      gW0, gW0t, gW1, gW1tb, gW2, gW2tb, Wih, WihRb,
      mW, mWb, p0W, p0Wb, p1W, p1Wb, batch, boffs, bih, bhh, bsum);
  k_h0<<<1, 256, 0, stream>>>(bsum, h0, c0);
  k_gconst<<<(4*Hh)/4, 256, 0, stream>>>(Wih, Whh, bsum, h0, gconst);

  // graph structure
  k_count<<<(Ee+255)/256, 256, 0, stream>>>(ei + Ee, counts);
  k_scan1<<<NSCAN, 256, 0, stream>>>(counts, spart, dinv);
  k_scan2<<<1, 128, 0, stream>>>(spart, NSCAN);
  k_scan3<<<NSCAN, 256, 0, stream>>>(counts, spart, offs, fptr);
  k_fill<<<(Ee+255)/256, 256, 0, stream>>>(ei, dinv, sto_x, fptr, epack, evoc);

  // layer 0: WG0 = weight@gW0 (bf16 table), half-wave table-gather conv
  {
    dim3 g((Hh+63)/64, (Vv+63)/64);
    k_gemm_nt<<<g, 256, 0, stream>>>(weight, gW0t, WG0b, Vv, DIN, Hh);
  }
  k_conv0<<<Nn/4, 256, 0, stream>>>(WG0b, sto_x, offs, epack, evoc, dinv, gb0, Xb);

  // layers 1,2: aggregate (half-wave gathers), 64x256 GEMM with fused epilogue
  k_agg<<<Nn/4, 256, 0, stream>>>(Xb, offs, epack, dinv, Tb);
  gemm64(Tb, Hh, gW1tb, gb1, nullptr, nullptr, nullptr, Xb, Nn, Hh, Hh, 1);
  k_agg<<<Nn/4, 256, 0, stream>>>(Xb, offs, epack, dinv, Tb);
  gemm64(Tb, Hh, gW2tb, gb2, sto_w, nullptr, nullptr, Xb, Nn, Hh, Hh, 0);  // Xb = wx

  // Set2Set with constant-folded step 0
  k_pool<<<Bb/4, 256, 0, stream>>>(Xb, h0, 0, boffs, r0b, Hh, sto, 1);
  gemm64(r0b, Hh, WihRb, gconst, nullptr, nullptr, gates, nullptr, Bb, Hh, 4*Hh, 0);
  k_lstm1<<<(Bb*Hh+255)/256, 256, 0, stream>>>(gates, c0, hbuf, qh2);
  k_pool<<<Bb/4, 256, 0, stream>>>(Xb, hbuf, 1, boffs, qh2 + Hh, 2*Hh, nullptr, 0);

  // head: mean = [h1|r1]@mW^T + mb + sto; normalize (bf16); bf16 MLP; final dot
  gemm64(qh2, 2*Hh, mWb, mb, nullptr, sto, meanb, nullptr, Bb, 2*Hh, Hh, 0);
  k_norm<<<Bb, Hh, 0, stream>>>(meanb, meanbb);
  gemm8(meanbb, Hh, p0Wb, p0b, nullptr, nullptr, nullptr, y0b, Bb, Hh, 128, 2);
  gemm8(y0b, 128, p1Wb, p1b, nullptr, nullptr, y1, nullptr, Bb, 128, 128, 2);
  k_out<<<Bb, 128, 0, stream>>>(y1, p2W, p2b, out);
}